// Round 9
// baseline (122.786 us; speedup 1.0000x reference)
//
#include <hip/hip_runtime.h>
#include <cstdint>
#include <cstddef>

typedef _Float16 f16;
typedef _Float16 f16x4 __attribute__((ext_vector_type(4)));
typedef _Float16 f16x8 __attribute__((ext_vector_type(8)));
typedef float f32x4 __attribute__((ext_vector_type(4)));

#define MFMA16(a, b, c) __builtin_amdgcn_mfma_f32_16x16x32_f16(a, b, c, 0, 0, 0)

static __device__ __forceinline__ void gld16(const void* g, void* l) {
  __builtin_amdgcn_global_load_lds(
      (const __attribute__((address_space(1))) void*)g,
      (__attribute__((address_space(3))) void*)l, 16, 0, 0);
}

#define B_ 4
#define N_ 4096
#define C_ 512
#define H_ 8
#define D_ 64
#define BN_ROWS 16384
#define QKV_COLS 1536

// ---------------- kernel 1: fp32 -> fp16 convert (x, Wqkv, Wproj) ----------------
__global__ __launch_bounds__(256) void k_convert(
    const float* __restrict__ x, const float* __restrict__ wqkv,
    const float* __restrict__ wproj,
    f16* __restrict__ xh, f16* __restrict__ wqkvh, f16* __restrict__ wprojh)
{
  const int NX  = (BN_ROWS * C_) / 4;
  const int NW1 = (QKV_COLS * C_) / 4;
  const int NW2 = (C_ * C_) / 4;
  const int total = NX + NW1 + NW2;
  const int stride = gridDim.x * blockDim.x;
  for (int i = blockIdx.x * blockDim.x + threadIdx.x; i < total; i += stride) {
    const float4* s; f16x4* d; int j;
    if (i < NX)              { s = (const float4*)x;     d = (f16x4*)xh;     j = i; }
    else if (i < NX + NW1)   { s = (const float4*)wqkv;  d = (f16x4*)wqkvh;  j = i - NX; }
    else                     { s = (const float4*)wproj; d = (f16x4*)wprojh; j = i - NX - NW1; }
    float4 v = s[j];
    f16x4 o; o[0] = (f16)v.x; o[1] = (f16)v.y; o[2] = (f16)v.z; o[3] = (f16)v.w;
    d[j] = o;
  }
}

// ---------------- kernel 2: QKV GEMM v4 — 2-slot dbuf, counted drain after MFMA
// BM=256, BN=128, BK=64, 512 thr (8 waves, 4m x 2n, wave tile 64x64), 96KB LDS,
// 1 block/CU, grid 768 = 3 exact full rounds. Proven BK=64 XOR layout (0 conflicts).
// Per K-step: issue stage(t+1) -> frags kk0 -> MFMA -> frags kk1 -> MFMA ->
// vmcnt(0) drain (after ~2 compute phases; A/B mostly L2-hot) -> ONE barrier.
__global__ __launch_bounds__(512, 1) void k_qkv_gemm(
    const f16* __restrict__ X, const f16* __restrict__ W, f16* __restrict__ Out)
{
  __shared__ f16 As[2][256][64];   // 64 KB
  __shared__ f16 Bs[2][128][64];   // 32 KB
  int w = (blockIdx.x & 7) * 96 + (blockIdx.x >> 3);   // XCD swizzle, 768 = 8*96
  const int m0 = (w / 12) * 256;
  const int n0 = (w % 12) * 128;
  const int tid = threadIdx.x;
  const int wid = tid >> 6, lane = tid & 63;
  const int lr = lane & 15, lg = lane >> 4;
  const int wm = wid >> 1, wn = wid & 1;               // wave tile 64x64
  const int sr = lane >> 3, sslot = (lane & 7) ^ sr;   // gld16 pre-swizzle
  f32x4 acc[4][4] = {};

#define STAGE(tt, s)                                                          \
  do {                                                                        \
    _Pragma("unroll")                                                         \
    for (int i = 0; i < 4; ++i) {                                             \
      int chunk = wid * 4 + i;                                                \
      gld16(&X[(size_t)(m0 + chunk * 8 + sr) * 512 + (tt) * 64 + sslot * 8],  \
            &As[s][chunk * 8][0]);                                            \
    }                                                                         \
    _Pragma("unroll")                                                         \
    for (int i = 0; i < 2; ++i) {                                             \
      int chunk = wid * 2 + i;                                                \
      gld16(&W[(size_t)(n0 + chunk * 8 + sr) * 512 + (tt) * 64 + sslot * 8],  \
            &Bs[s][chunk * 8][0]);                                            \
    }                                                                         \
  } while (0)

  STAGE(0, 0);
  asm volatile("s_waitcnt vmcnt(0)" ::: "memory");
  __builtin_amdgcn_s_barrier();
  asm volatile("" ::: "memory");

#pragma unroll
  for (int t = 0; t < 8; ++t) {
    const int p = t & 1, q = p ^ 1;
    if (t < 7) STAGE(t + 1, q);
    // ---- phase 0: kk = 0 ----
    {
      f16x8 af[4], bf[4];
#pragma unroll
      for (int m = 0; m < 4; ++m)
        af[m] = *(const f16x8*)&As[p][wm * 64 + m * 16 + lr][((lg ^ (lr & 7)) * 8)];
#pragma unroll
      for (int n = 0; n < 4; ++n)
        bf[n] = *(const f16x8*)&Bs[p][wn * 64 + n * 16 + lr][((lg ^ (lr & 7)) * 8)];
      asm volatile("s_waitcnt lgkmcnt(0)" ::: "memory");
      __builtin_amdgcn_sched_barrier(0);
      __builtin_amdgcn_s_setprio(1);
#pragma unroll
      for (int m = 0; m < 4; ++m)
#pragma unroll
        for (int n = 0; n < 4; ++n)
          acc[m][n] = MFMA16(bf[n], af[m], acc[m][n]);   // swapped operands
      __builtin_amdgcn_s_setprio(0);
    }
    // ---- phase 1: kk = 1 ----
    {
      f16x8 af[4], bf[4];
#pragma unroll
      for (int m = 0; m < 4; ++m)
        af[m] = *(const f16x8*)&As[p][wm * 64 + m * 16 + lr][((((4 + lg)) ^ (lr & 7)) * 8)];
#pragma unroll
      for (int n = 0; n < 4; ++n)
        bf[n] = *(const f16x8*)&Bs[p][wn * 64 + n * 16 + lr][((((4 + lg)) ^ (lr & 7)) * 8)];
      asm volatile("s_waitcnt lgkmcnt(0)" ::: "memory");
      __builtin_amdgcn_sched_barrier(0);
      __builtin_amdgcn_s_setprio(1);
#pragma unroll
      for (int m = 0; m < 4; ++m)
#pragma unroll
        for (int n = 0; n < 4; ++n)
          acc[m][n] = MFMA16(bf[n], af[m], acc[m][n]);
      __builtin_amdgcn_s_setprio(0);
    }
    if (t < 7) {
      asm volatile("s_waitcnt vmcnt(0)" ::: "memory");   // tile t+1 landed
      __builtin_amdgcn_s_barrier();
      asm volatile("" ::: "memory");
    }
  }
#undef STAGE

#pragma unroll
  for (int m = 0; m < 4; ++m)
#pragma unroll
    for (int n = 0; n < 4; ++n) {
      int row = m0 + wm * 64 + m * 16 + lr;
      int col = n0 + wn * 64 + n * 16 + lg * 4;
      f16x4 o;
      bool relu = (col < 1024);
#pragma unroll
      for (int j = 0; j < 4; ++j) {
        float v = acc[m][n][j];
        if (relu) v = fmaxf(v, 0.f);
        o[j] = (f16)v;
      }
      *(f16x4*)&Out[(size_t)row * QKV_COLS + col] = o;
    }
}

// ---------------- kernel 3: partial K^T V — R2 exact ----------------
__global__ __launch_bounds__(256) void k_ktv(
    const f16* __restrict__ qkv, float* __restrict__ partial, float* __restrict__ pksum)
{
  __shared__ f16 ks[32][64];
  __shared__ f16 vs[32][64];
  const int bh = blockIdx.x, sp = blockIdx.y;
  const int b = bh >> 3, h = bh & 7;
  const int tid = threadIdx.x, wid = tid >> 6, lane = tid & 63;
  const int srow = lane >> 3, scol = (lane & 7) * 8;
  const int td = (wid << 2) | (lane >> 4);
  const int te = lane & 15;
  float acc[4][4] = {};
  float ksacc[4] = {0.f, 0.f, 0.f, 0.f};
  const size_t rowbase = (size_t)b * N_ + sp * 128;
  for (int t = 0; t < 4; ++t) {
    int nb = t * 32 + wid * 8 + srow;
    gld16(&qkv[(rowbase + nb) * QKV_COLS + 512 + h * 64 + scol], &ks[wid * 8][0]);
    gld16(&qkv[(rowbase + nb) * QKV_COLS + 1024 + h * 64 + scol], &vs[wid * 8][0]);
    __syncthreads();
#pragma unroll 4
    for (int n = 0; n < 32; ++n) {
      f16x4 kd = *(const f16x4*)&ks[n][td * 4];
      f16x4 ve = *(const f16x4*)&vs[n][te * 4];
      float kf[4], vf[4];
#pragma unroll
      for (int i = 0; i < 4; ++i) { kf[i] = (float)kd[i]; vf[i] = (float)ve[i]; }
#pragma unroll
      for (int i = 0; i < 4; ++i)
#pragma unroll
        for (int j = 0; j < 4; ++j)
          acc[i][j] += kf[i] * vf[j];
      if (te == 0) {
#pragma unroll
        for (int i = 0; i < 4; ++i) ksacc[i] += kf[i];
      }
    }
    __syncthreads();
  }
  float* pp = partial + (size_t)(bh * 32 + sp) * 4096;
#pragma unroll
  for (int i = 0; i < 4; ++i)
#pragma unroll
    for (int j = 0; j < 4; ++j)
      pp[(td * 4 + i) * 64 + te * 4 + j] = acc[i][j];
  if (te == 0) {
    float* kp = pksum + (bh * 32 + sp) * 64;
#pragma unroll
    for (int i = 0; i < 4; ++i) kp[td * 4 + i] = ksacc[i];
  }
}

// ---------------- kernel 4: reduce 32 partials — R2 exact ----------------
__global__ __launch_bounds__(256) void k_reduce(
    const float* __restrict__ partial, const float* __restrict__ pksum,
    float* __restrict__ attn_acc, float* __restrict__ ksum)
{
  const int bh = blockIdx.x, seg = blockIdx.y, tid = threadIdx.x;
  const int i = seg * 256 + tid;
  float s = 0.f;
#pragma unroll 8
  for (int sp = 0; sp < 32; ++sp) s += partial[(size_t)(bh * 32 + sp) * 4096 + i];
  attn_acc[bh * 4096 + i] = s;
  if (seg == 0 && tid < 64) {
    float t2 = 0.f;
#pragma unroll 8
    for (int sp = 0; sp < 32; ++sp) t2 += pksum[(bh * 32 + sp) * 64 + tid];
    ksum[bh * 64 + tid] = t2;
  }
}

// ---------------- kernel 5: FUSED attn1 + proj — R8 exact ----------------
__global__ __launch_bounds__(256, 1) void k_attn_proj(
    const f16* __restrict__ qkv, const float* __restrict__ attn_acc,
    const float* __restrict__ ksum, const float* __restrict__ temp,
    const f16* __restrict__ Wp, const float* __restrict__ bias,
    float* __restrict__ attn1_out, float* __restrict__ Y)
{
  __shared__ f16 attnT[64][64];
  __shared__ f16 qs[64][64];
  __shared__ f16 outs[64][512];
  __shared__ f16 Bs[2][256][64];
  __shared__ float ksum_s[512];
  __shared__ float bias_s[512];
  __shared__ float denom_s[64];

  const int bid = blockIdx.x;
  const int b = bid >> 6, sp = bid & 63;
  const size_t gr = (size_t)b * N_ + sp * 64;
  const int tid = threadIdx.x;
  const int wid = tid >> 6, lane = tid & 63;
  const int lr = lane & 15, lg = lane >> 4;
  const int sr = lane >> 3, sslot = (lane & 7) ^ sr;

  ksum_s[tid]       = ksum[b * 512 + tid];
  ksum_s[tid + 256] = ksum[b * 512 + tid + 256];
  bias_s[tid]       = bias[tid];
  bias_s[tid + 256] = bias[tid + 256];

  // ================= Phase A: attn1 per head =================
  for (int h = 0; h < 8; ++h) {
    const float tsc = temp[h];
    {
      int e = tid & 63, dblk = (tid >> 6) * 16;
      float vals[16];
#pragma unroll
      for (int x = 0; x < 16; ++x)
        vals[x] = attn_acc[(size_t)(b * 8 + h) * 4096 + (dblk + x) * 64 + e] * tsc;
#pragma unroll
      for (int half = 0; half < 2; ++half) {
        int slot = ((dblk >> 3) + half) ^ (e & 7);
        f16x8 pk;
#pragma unroll
        for (int j = 0; j < 8; ++j) pk[j] = (f16)vals[half * 8 + j];
        *(f16x8*)&attnT[e][slot * 8] = pk;
      }
    }
#pragma unroll
    for (int rr = 0; rr < 2; ++rr) {
      int row = rr * 32 + wid * 8;
      gld16(&qkv[(gr + row + sr) * QKV_COLS + h * 64 + sslot * 8], &qs[row][0]);
    }
    __syncthreads();
    if (tid < 64) {
      int r = tid;
      float dot = 0.f;
#pragma unroll
      for (int c = 0; c < 8; ++c) {
        f16x8 qv = *(const f16x8*)&qs[r][((c ^ (r & 7)) * 8)];
#pragma unroll
        for (int j = 0; j < 8; ++j) dot += (float)qv[j] * ksum_s[h * 64 + c * 8 + j];
      }
      denom_s[r] = fmaxf(dot, 100.f);
    }
    const int arow = wid * 16 + lr;
    f16x8 af[2], bf[4][2];
#pragma unroll
    for (int kk = 0; kk < 2; ++kk)
      af[kk] = *(const f16x8*)&qs[arow][(((kk * 4 + lg) ^ (lr & 7)) * 8)];
#pragma unroll
    for (int et = 0; et < 4; ++et)
#pragma unroll
      for (int kk = 0; kk < 2; ++kk)
        bf[et][kk] = *(const f16x8*)&attnT[et * 16 + lr][(((kk * 4 + lg) ^ (lr & 7)) * 8)];
    f32x4 acc1[4] = {};
#pragma unroll
    for (int kk = 0; kk < 2; ++kk)
#pragma unroll
      for (int et = 0; et < 4; ++et)
        acc1[et] = MFMA16(bf[et][kk], af[kk], acc1[et]);
    __syncthreads();
    {
      const int rl = wid * 16 + lr;
      const float dn = denom_s[rl];
#pragma unroll
      for (int et = 0; et < 4; ++et) {
        int e = et * 16 + lg * 4;
        float4 o;
        o.x = acc1[et][0]; o.y = acc1[et][1]; o.z = acc1[et][2]; o.w = acc1[et][3];
        *(float4*)&attn1_out[((size_t)(b * 8 + h) * N_ + sp * 64 + rl) * 64 + e] = o;
        f16x4 oh;
#pragma unroll
        for (int j = 0; j < 4; ++j) oh[j] = (f16)(acc1[et][j] / dn);
        int c = h * 64 + e;
        *(f16x4*)((char*)&outs[0][0] + rl * 1024 +
                  (((c >> 3) ^ (rl & 7)) * 16) + (lg & 1) * 8) = oh;
      }
    }
  }
  __syncthreads();

  // ================= Phase B: proj =================
  f32x4 accP0[4][4] = {};
  f32x4 accP1[4][4] = {};

#define STAGEP(hf_, kc_, bufi)                                                \
  do {                                                                        \
    _Pragma("unroll")                                                         \
    for (int rd = 0; rd < 8; ++rd) {                                          \
      int row = rd * 32 + wid * 8;                                            \
      gld16(&Wp[(size_t)((hf_) * 256 + row + sr) * 512 + (kc_) * 64 + sslot * 8], \
            &Bs[bufi][row][0]);                                               \
    }                                                                         \
  } while (0)

  STAGEP(0, 0, 0);
  __syncthreads();

  for (int kc = 0; kc < 8; ++kc) {
    STAGEP(1, kc, 1);
    f16x8 afp[2][4];
#pragma unroll
    for (int kk = 0; kk < 2; ++kk)
#pragma unroll
      for (int m = 0; m < 4; ++m) {
        int row = m * 16 + lr;
        afp[kk][m] = *(const f16x8*)((const char*)&outs[0][0] + row * 1024 +
                      (((kc * 8 + kk * 4 + lg) ^ (row & 7)) * 16));
      }
    {
      f16x8 bfp[4];
#pragma unroll
      for (int kk = 0; kk < 2; ++kk) {
#pragma unroll
        for (int n = 0; n < 4; ++n)
          bfp[n] = *(const f16x8*)&Bs[0][wid * 64 + n * 16 + lr][(((kk * 4 + lg) ^ (lr & 7)) * 8)];
#pragma unroll
        for (int m = 0; m < 4; ++m)
#pragma unroll
          for (int n = 0; n < 4; ++n)
            accP0[m][n] = MFMA16(bfp[n], afp[kk][m], accP0[m][n]);
      }
    }
    __syncthreads();
    if (kc < 7) STAGEP(0, kc + 1, 0);
    {
      f16x8 bfp[4];
#pragma unroll
      for (int kk = 0; kk < 2; ++kk) {
#pragma unroll
        for (int n = 0; n < 4; ++n)
          bfp[n] = *(const f16x8*)&Bs[1][wid * 64 + n * 16 + lr][(((kk * 4 + lg) ^ (lr & 7)) * 8)];
#pragma unroll
        for (int m = 0; m < 4; ++m)
#pragma unroll
          for (int n = 0; n < 4; ++n)
            accP1[m][n] = MFMA16(bfp[n], afp[kk][m], accP1[m][n]);
      }
    }
    __syncthreads();
  }
#undef STAGEP

#pragma unroll
  for (int m = 0; m < 4; ++m)
#pragma unroll
    for (int n = 0; n < 4; ++n) {
      size_t row = gr + m * 16 + lr;
      int col0 = wid * 64 + n * 16 + lg * 4;
      float4 o0;
      o0.x = accP0[m][n][0] + bias_s[col0 + 0];
      o0.y = accP0[m][n][1] + bias_s[col0 + 1];
      o0.z = accP0[m][n][2] + bias_s[col0 + 2];
      o0.w = accP0[m][n][3] + bias_s[col0 + 3];
      *(float4*)&Y[row * C_ + col0] = o0;
      int col1 = col0 + 256;
      float4 o1;
      o1.x = accP1[m][n][0] + bias_s[col1 + 0];
      o1.y = accP1[m][n][1] + bias_s[col1 + 1];
      o1.z = accP1[m][n][2] + bias_s[col1 + 2];
      o1.w = accP1[m][n][3] + bias_s[col1 + 3];
      *(float4*)&Y[row * C_ + col1] = o1;
    }
}

extern "C" void kernel_launch(void* const* d_in, const int* in_sizes, int n_in,
                              void* d_out, int out_size, void* d_ws, size_t ws_size,
                              hipStream_t stream)
{
  const float* x     = (const float*)d_in[0];
  const float* wqkv  = (const float*)d_in[1];
  const float* temp  = (const float*)d_in[2];
  const float* wproj = (const float*)d_in[3];
  const float* bproj = (const float*)d_in[4];
  float* y_out     = (float*)d_out;
  float* attn1_out = (float*)d_out + 8388608;

  char* ws = (char*)d_ws;
  f16*   xh       = (f16*)(ws);                   // 16 MB; reused as `partial` after QKV
  float* partial  = (float*)(ws);                 // aliases xh (xh dead once qkv done)
  f16*   wqkvh    = (f16*)(ws + 16777216);
  f16*   wprojh   = (f16*)(ws + 18350080);
  f16*   qkvh     = (f16*)(ws + 18874368);
  float* attn_acc = (float*)(ws + 69206016);
  float* ksum     = (float*)(ws + 69730304);
  float* pksum    = (float*)(ws + 69738496);

  hipLaunchKernelGGL(k_convert,   dim3(2048),   dim3(256), 0, stream, x, wqkv, wproj, xh, wqkvh, wprojh);
  // QKV: 64 m-tiles (256) x 12 n-tiles (128) = 768 blocks = 3 exact rounds at 1 block/CU
  hipLaunchKernelGGL(k_qkv_gemm,  dim3(768),    dim3(512), 0, stream, xh, wqkvh, qkvh);
  hipLaunchKernelGGL(k_ktv,       dim3(32, 32), dim3(256), 0, stream, qkvh, partial, pksum);
  hipLaunchKernelGGL(k_reduce,    dim3(32, 16), dim3(256), 0, stream, partial, pksum, attn_acc, ksum);
  hipLaunchKernelGGL(k_attn_proj, dim3(256),    dim3(256), 0, stream,
                     qkvh, attn_acc, ksum, temp, wprojh, bproj, attn1_out, y_out);
}

// Round 10
// 122.113 us; speedup vs baseline: 1.0055x; 1.0055x over previous
//
#include <hip/hip_runtime.h>
#include <cstdint>
#include <cstddef>

typedef _Float16 f16;
typedef _Float16 f16x4 __attribute__((ext_vector_type(4)));
typedef _Float16 f16x8 __attribute__((ext_vector_type(8)));
typedef float f32x4 __attribute__((ext_vector_type(4)));

#define MFMA16(a, b, c) __builtin_amdgcn_mfma_f32_16x16x32_f16(a, b, c, 0, 0, 0)

static __device__ __forceinline__ void gld16(const void* g, void* l) {
  __builtin_amdgcn_global_load_lds(
      (const __attribute__((address_space(1))) void*)g,
      (__attribute__((address_space(3))) void*)l, 16, 0, 0);
}

#define B_ 4
#define N_ 4096
#define C_ 512
#define H_ 8
#define D_ 64
#define BN_ROWS 16384
#define QKV_COLS 1536

// ---------------- kernel 1: fp32 -> fp16 convert (x, Wqkv, Wproj) ----------------
__global__ __launch_bounds__(256) void k_convert(
    const float* __restrict__ x, const float* __restrict__ wqkv,
    const float* __restrict__ wproj,
    f16* __restrict__ xh, f16* __restrict__ wqkvh, f16* __restrict__ wprojh)
{
  const int NX  = (BN_ROWS * C_) / 4;
  const int NW1 = (QKV_COLS * C_) / 4;
  const int NW2 = (C_ * C_) / 4;
  const int total = NX + NW1 + NW2;
  const int stride = gridDim.x * blockDim.x;
  for (int i = blockIdx.x * blockDim.x + threadIdx.x; i < total; i += stride) {
    const float4* s; f16x4* d; int j;
    if (i < NX)              { s = (const float4*)x;     d = (f16x4*)xh;     j = i; }
    else if (i < NX + NW1)   { s = (const float4*)wqkv;  d = (f16x4*)wqkvh;  j = i - NX; }
    else                     { s = (const float4*)wproj; d = (f16x4*)wprojh; j = i - NX - NW1; }
    float4 v = s[j];
    f16x4 o; o[0] = (f16)v.x; o[1] = (f16)v.y; o[2] = (f16)v.z; o[3] = (f16)v.w;
    d[j] = o;
  }
}

// ---------------- kernel 2: QKV GEMM v5 — 3-slot pipeline, COUNTED vmcnt (T4)
// BM=256, BN=128, BK=64, 512 thr (8 waves, wave tile 64x64), 144KB LDS (3 slots),
// 1 block/CU, grid 768 = 3 exact rounds. Zero-conflict BK=64 XOR layout.
// Iter t: issue STAGE(t+2) -> 2 MFMA phases on slot t%3 -> s_waitcnt vmcnt(6)
// (tile t+1 landed, t+2's 6 loads STILL IN FLIGHT — never 0 until t==6) -> barrier.
// Each tile gets ~2 iterations (>600cy) of latency cover.
__global__ __launch_bounds__(512, 1) void k_qkv_gemm(
    const f16* __restrict__ X, const f16* __restrict__ W, f16* __restrict__ Out)
{
  __shared__ f16 As[3][256][64];   // 96 KB
  __shared__ f16 Bs[3][128][64];   // 48 KB
  int w = (blockIdx.x & 7) * 96 + (blockIdx.x >> 3);   // XCD swizzle, 768 = 8*96
  const int m0 = (w / 12) * 256;
  const int n0 = (w % 12) * 128;
  const int tid = threadIdx.x;
  const int wid = tid >> 6, lane = tid & 63;
  const int lr = lane & 15, lg = lane >> 4;
  const int wm = wid >> 1, wn = wid & 1;               // wave tile 64x64
  const int sr = lane >> 3, sslot = (lane & 7) ^ sr;   // gld16 pre-swizzle
  f32x4 acc[4][4] = {};

#define STAGE(tt, s)                                                          \
  do {                                                                        \
    _Pragma("unroll")                                                         \
    for (int i = 0; i < 4; ++i) {                                             \
      int chunk = wid * 4 + i;                                                \
      gld16(&X[(size_t)(m0 + chunk * 8 + sr) * 512 + (tt) * 64 + sslot * 8],  \
            &As[s][chunk * 8][0]);                                            \
    }                                                                         \
    _Pragma("unroll")                                                         \
    for (int i = 0; i < 2; ++i) {                                             \
      int chunk = wid * 2 + i;                                                \
      gld16(&W[(size_t)(n0 + chunk * 8 + sr) * 512 + (tt) * 64 + sslot * 8],  \
            &Bs[s][chunk * 8][0]);                                            \
    }                                                                         \
  } while (0)

  // prologue: tiles 0,1 in flight; wait only for tile 0
  STAGE(0, 0);
  STAGE(1, 1);
  asm volatile("s_waitcnt vmcnt(6)" ::: "memory");
  __builtin_amdgcn_s_barrier();
  asm volatile("" ::: "memory");

#pragma unroll
  for (int t = 0; t < 8; ++t) {
    const int p = t % 3;
    if (t + 2 < 8) STAGE(t + 2, (t + 2) % 3);
    // ---- phase 0: kk = 0 ----
    {
      f16x8 af[4], bf[4];
#pragma unroll
      for (int m = 0; m < 4; ++m)
        af[m] = *(const f16x8*)&As[p][wm * 64 + m * 16 + lr][((lg ^ (lr & 7)) * 8)];
#pragma unroll
      for (int n = 0; n < 4; ++n)
        bf[n] = *(const f16x8*)&Bs[p][wn * 64 + n * 16 + lr][((lg ^ (lr & 7)) * 8)];
      asm volatile("s_waitcnt lgkmcnt(0)" ::: "memory");
      __builtin_amdgcn_sched_barrier(0);
      __builtin_amdgcn_s_setprio(1);
#pragma unroll
      for (int m = 0; m < 4; ++m)
#pragma unroll
        for (int n = 0; n < 4; ++n)
          acc[m][n] = MFMA16(bf[n], af[m], acc[m][n]);   // swapped operands
      __builtin_amdgcn_s_setprio(0);
    }
    // ---- phase 1: kk = 1 ----
    {
      f16x8 af[4], bf[4];
#pragma unroll
      for (int m = 0; m < 4; ++m)
        af[m] = *(const f16x8*)&As[p][wm * 64 + m * 16 + lr][(((4 + lg) ^ (lr & 7)) * 8)];
#pragma unroll
      for (int n = 0; n < 4; ++n)
        bf[n] = *(const f16x8*)&Bs[p][wn * 64 + n * 16 + lr][(((4 + lg) ^ (lr & 7)) * 8)];
      asm volatile("s_waitcnt lgkmcnt(0)" ::: "memory");
      __builtin_amdgcn_sched_barrier(0);
      __builtin_amdgcn_s_setprio(1);
#pragma unroll
      for (int m = 0; m < 4; ++m)
#pragma unroll
        for (int n = 0; n < 4; ++n)
          acc[m][n] = MFMA16(bf[n], af[m], acc[m][n]);
      __builtin_amdgcn_s_setprio(0);
    }
    // ---- counted wait: tile t+1 landed, tile t+2 still flying ----
    if (t < 6) {
      asm volatile("s_waitcnt vmcnt(6)" ::: "memory");
      __builtin_amdgcn_s_barrier();
      asm volatile("" ::: "memory");
    } else if (t == 6) {
      asm volatile("s_waitcnt vmcnt(0)" ::: "memory");
      __builtin_amdgcn_s_barrier();
      asm volatile("" ::: "memory");
    }
  }
#undef STAGE

#pragma unroll
  for (int m = 0; m < 4; ++m)
#pragma unroll
    for (int n = 0; n < 4; ++n) {
      int row = m0 + wm * 64 + m * 16 + lr;
      int col = n0 + wn * 64 + n * 16 + lg * 4;
      f16x4 o;
      bool relu = (col < 1024);
#pragma unroll
      for (int j = 0; j < 4; ++j) {
        float v = acc[m][n][j];
        if (relu) v = fmaxf(v, 0.f);
        o[j] = (f16)v;
      }
      *(f16x4*)&Out[(size_t)row * QKV_COLS + col] = o;
    }
}

// ---------------- kernel 3: partial K^T V — R2 exact ----------------
__global__ __launch_bounds__(256) void k_ktv(
    const f16* __restrict__ qkv, float* __restrict__ partial, float* __restrict__ pksum)
{
  __shared__ f16 ks[32][64];
  __shared__ f16 vs[32][64];
  const int bh = blockIdx.x, sp = blockIdx.y;
  const int b = bh >> 3, h = bh & 7;
  const int tid = threadIdx.x, wid = tid >> 6, lane = tid & 63;
  const int srow = lane >> 3, scol = (lane & 7) * 8;
  const int td = (wid << 2) | (lane >> 4);
  const int te = lane & 15;
  float acc[4][4] = {};
  float ksacc[4] = {0.f, 0.f, 0.f, 0.f};
  const size_t rowbase = (size_t)b * N_ + sp * 128;
  for (int t = 0; t < 4; ++t) {
    int nb = t * 32 + wid * 8 + srow;
    gld16(&qkv[(rowbase + nb) * QKV_COLS + 512 + h * 64 + scol], &ks[wid * 8][0]);
    gld16(&qkv[(rowbase + nb) * QKV_COLS + 1024 + h * 64 + scol], &vs[wid * 8][0]);
    __syncthreads();
#pragma unroll 4
    for (int n = 0; n < 32; ++n) {
      f16x4 kd = *(const f16x4*)&ks[n][td * 4];
      f16x4 ve = *(const f16x4*)&vs[n][te * 4];
      float kf[4], vf[4];
#pragma unroll
      for (int i = 0; i < 4; ++i) { kf[i] = (float)kd[i]; vf[i] = (float)ve[i]; }
#pragma unroll
      for (int i = 0; i < 4; ++i)
#pragma unroll
        for (int j = 0; j < 4; ++j)
          acc[i][j] += kf[i] * vf[j];
      if (te == 0) {
#pragma unroll
        for (int i = 0; i < 4; ++i) ksacc[i] += kf[i];
      }
    }
    __syncthreads();
  }
  float* pp = partial + (size_t)(bh * 32 + sp) * 4096;
#pragma unroll
  for (int i = 0; i < 4; ++i)
#pragma unroll
    for (int j = 0; j < 4; ++j)
      pp[(td * 4 + i) * 64 + te * 4 + j] = acc[i][j];
  if (te == 0) {
    float* kp = pksum + (bh * 32 + sp) * 64;
#pragma unroll
    for (int i = 0; i < 4; ++i) kp[td * 4 + i] = ksacc[i];
  }
}

// ---------------- kernel 4: reduce 32 partials — R2 exact ----------------
__global__ __launch_bounds__(256) void k_reduce(
    const float* __restrict__ partial, const float* __restrict__ pksum,
    float* __restrict__ attn_acc, float* __restrict__ ksum)
{
  const int bh = blockIdx.x, seg = blockIdx.y, tid = threadIdx.x;
  const int i = seg * 256 + tid;
  float s = 0.f;
#pragma unroll 8
  for (int sp = 0; sp < 32; ++sp) s += partial[(size_t)(bh * 32 + sp) * 4096 + i];
  attn_acc[bh * 4096 + i] = s;
  if (seg == 0 && tid < 64) {
    float t2 = 0.f;
#pragma unroll 8
    for (int sp = 0; sp < 32; ++sp) t2 += pksum[(bh * 32 + sp) * 64 + tid];
    ksum[bh * 64 + tid] = t2;
  }
}

// ---------------- kernel 5: FUSED attn1 + proj — R8 exact ----------------
__global__ __launch_bounds__(256, 1) void k_attn_proj(
    const f16* __restrict__ qkv, const float* __restrict__ attn_acc,
    const float* __restrict__ ksum, const float* __restrict__ temp,
    const f16* __restrict__ Wp, const float* __restrict__ bias,
    float* __restrict__ attn1_out, float* __restrict__ Y)
{
  __shared__ f16 attnT[64][64];
  __shared__ f16 qs[64][64];
  __shared__ f16 outs[64][512];
  __shared__ f16 Bs[2][256][64];
  __shared__ float ksum_s[512];
  __shared__ float bias_s[512];
  __shared__ float denom_s[64];

  const int bid = blockIdx.x;
  const int b = bid >> 6, sp = bid & 63;
  const size_t gr = (size_t)b * N_ + sp * 64;
  const int tid = threadIdx.x;
  const int wid = tid >> 6, lane = tid & 63;
  const int lr = lane & 15, lg = lane >> 4;
  const int sr = lane >> 3, sslot = (lane & 7) ^ sr;

  ksum_s[tid]       = ksum[b * 512 + tid];
  ksum_s[tid + 256] = ksum[b * 512 + tid + 256];
  bias_s[tid]       = bias[tid];
  bias_s[tid + 256] = bias[tid + 256];

  // ================= Phase A: attn1 per head =================
  for (int h = 0; h < 8; ++h) {
    const float tsc = temp[h];
    {
      int e = tid & 63, dblk = (tid >> 6) * 16;
      float vals[16];
#pragma unroll
      for (int x = 0; x < 16; ++x)
        vals[x] = attn_acc[(size_t)(b * 8 + h) * 4096 + (dblk + x) * 64 + e] * tsc;
#pragma unroll
      for (int half = 0; half < 2; ++half) {
        int slot = ((dblk >> 3) + half) ^ (e & 7);
        f16x8 pk;
#pragma unroll
        for (int j = 0; j < 8; ++j) pk[j] = (f16)vals[half * 8 + j];
        *(f16x8*)&attnT[e][slot * 8] = pk;
      }
    }
#pragma unroll
    for (int rr = 0; rr < 2; ++rr) {
      int row = rr * 32 + wid * 8;
      gld16(&qkv[(gr + row + sr) * QKV_COLS + h * 64 + sslot * 8], &qs[row][0]);
    }
    __syncthreads();
    if (tid < 64) {
      int r = tid;
      float dot = 0.f;
#pragma unroll
      for (int c = 0; c < 8; ++c) {
        f16x8 qv = *(const f16x8*)&qs[r][((c ^ (r & 7)) * 8)];
#pragma unroll
        for (int j = 0; j < 8; ++j) dot += (float)qv[j] * ksum_s[h * 64 + c * 8 + j];
      }
      denom_s[r] = fmaxf(dot, 100.f);
    }
    const int arow = wid * 16 + lr;
    f16x8 af[2], bf[4][2];
#pragma unroll
    for (int kk = 0; kk < 2; ++kk)
      af[kk] = *(const f16x8*)&qs[arow][(((kk * 4 + lg) ^ (lr & 7)) * 8)];
#pragma unroll
    for (int et = 0; et < 4; ++et)
#pragma unroll
      for (int kk = 0; kk < 2; ++kk)
        bf[et][kk] = *(const f16x8*)&attnT[et * 16 + lr][(((kk * 4 + lg) ^ (lr & 7)) * 8)];
    f32x4 acc1[4] = {};
#pragma unroll
    for (int kk = 0; kk < 2; ++kk)
#pragma unroll
      for (int et = 0; et < 4; ++et)
        acc1[et] = MFMA16(bf[et][kk], af[kk], acc1[et]);
    __syncthreads();
    {
      const int rl = wid * 16 + lr;
      const float dn = denom_s[rl];
#pragma unroll
      for (int et = 0; et < 4; ++et) {
        int e = et * 16 + lg * 4;
        float4 o;
        o.x = acc1[et][0]; o.y = acc1[et][1]; o.z = acc1[et][2]; o.w = acc1[et][3];
        *(float4*)&attn1_out[((size_t)(b * 8 + h) * N_ + sp * 64 + rl) * 64 + e] = o;
        f16x4 oh;
#pragma unroll
        for (int j = 0; j < 4; ++j) oh[j] = (f16)(acc1[et][j] / dn);
        int c = h * 64 + e;
        *(f16x4*)((char*)&outs[0][0] + rl * 1024 +
                  (((c >> 3) ^ (rl & 7)) * 16) + (lg & 1) * 8) = oh;
      }
    }
  }
  __syncthreads();

  // ================= Phase B: proj =================
  f32x4 accP0[4][4] = {};
  f32x4 accP1[4][4] = {};

#define STAGEP(hf_, kc_, bufi)                                                \
  do {                                                                        \
    _Pragma("unroll")                                                         \
    for (int rd = 0; rd < 8; ++rd) {                                          \
      int row = rd * 32 + wid * 8;                                            \
      gld16(&Wp[(size_t)((hf_) * 256 + row + sr) * 512 + (kc_) * 64 + sslot * 8], \
            &Bs[bufi][row][0]);                                               \
    }                                                                         \
  } while (0)

  STAGEP(0, 0, 0);
  __syncthreads();

  for (int kc = 0; kc < 8; ++kc) {
    STAGEP(1, kc, 1);
    f16x8 afp[2][4];
#pragma unroll
    for (int kk = 0; kk < 2; ++kk)
#pragma unroll
      for (int m = 0; m < 4; ++m) {
        int row = m * 16 + lr;
        afp[kk][m] = *(const f16x8*)((const char*)&outs[0][0] + row * 1024 +
                      (((kc * 8 + kk * 4 + lg) ^ (row & 7)) * 16));
      }
    {
      f16x8 bfp[4];
#pragma unroll
      for (int kk = 0; kk < 2; ++kk) {
#pragma unroll
        for (int n = 0; n < 4; ++n)
          bfp[n] = *(const f16x8*)&Bs[0][wid * 64 + n * 16 + lr][(((kk * 4 + lg) ^ (lr & 7)) * 8)];
#pragma unroll
        for (int m = 0; m < 4; ++m)
#pragma unroll
          for (int n = 0; n < 4; ++n)
            accP0[m][n] = MFMA16(bfp[n], afp[kk][m], accP0[m][n]);
      }
    }
    __syncthreads();
    if (kc < 7) STAGEP(0, kc + 1, 0);
    {
      f16x8 bfp[4];
#pragma unroll
      for (int kk = 0; kk < 2; ++kk) {
#pragma unroll
        for (int n = 0; n < 4; ++n)
          bfp[n] = *(const f16x8*)&Bs[1][wid * 64 + n * 16 + lr][(((kk * 4 + lg) ^ (lr & 7)) * 8)];
#pragma unroll
        for (int m = 0; m < 4; ++m)
#pragma unroll
          for (int n = 0; n < 4; ++n)
            accP1[m][n] = MFMA16(bfp[n], afp[kk][m], accP1[m][n]);
      }
    }
    __syncthreads();
  }
#undef STAGEP

#pragma unroll
  for (int m = 0; m < 4; ++m)
#pragma unroll
    for (int n = 0; n < 4; ++n) {
      size_t row = gr + m * 16 + lr;
      int col0 = wid * 64 + n * 16 + lg * 4;
      float4 o0;
      o0.x = accP0[m][n][0] + bias_s[col0 + 0];
      o0.y = accP0[m][n][1] + bias_s[col0 + 1];
      o0.z = accP0[m][n][2] + bias_s[col0 + 2];
      o0.w = accP0[m][n][3] + bias_s[col0 + 3];
      *(float4*)&Y[row * C_ + col0] = o0;
      int col1 = col0 + 256;
      float4 o1;
      o1.x = accP1[m][n][0] + bias_s[col1 + 0];
      o1.y = accP1[m][n][1] + bias_s[col1 + 1];
      o1.z = accP1[m][n][2] + bias_s[col1 + 2];
      o1.w = accP1[m][n][3] + bias_s[col1 + 3];
      *(float4*)&Y[row * C_ + col1] = o1;
    }
}

extern "C" void kernel_launch(void* const* d_in, const int* in_sizes, int n_in,
                              void* d_out, int out_size, void* d_ws, size_t ws_size,
                              hipStream_t stream)
{
  const float* x     = (const float*)d_in[0];
  const float* wqkv  = (const float*)d_in[1];
  const float* temp  = (const float*)d_in[2];
  const float* wproj = (const float*)d_in[3];
  const float* bproj = (const float*)d_in[4];
  float* y_out     = (float*)d_out;
  float* attn1_out = (float*)d_out + 8388608;

  char* ws = (char*)d_ws;
  f16*   xh       = (f16*)(ws);                   // 16 MB; reused as `partial` after QKV
  float* partial  = (float*)(ws);                 // aliases xh (xh dead once qkv done)
  f16*   wqkvh    = (f16*)(ws + 16777216);
  f16*   wprojh   = (f16*)(ws + 18350080);
  f16*   qkvh     = (f16*)(ws + 18874368);
  float* attn_acc = (float*)(ws + 69206016);
  float* ksum     = (float*)(ws + 69730304);
  float* pksum    = (float*)(ws + 69738496);

  hipLaunchKernelGGL(k_convert,   dim3(2048),   dim3(256), 0, stream, x, wqkv, wproj, xh, wqkvh, wprojh);
  // QKV: 64 m-tiles (256) x 12 n-tiles (128) = 768 blocks = 3 exact rounds at 1 block/CU
  hipLaunchKernelGGL(k_qkv_gemm,  dim3(768),    dim3(512), 0, stream, xh, wqkvh, qkvh);
  hipLaunchKernelGGL(k_ktv,       dim3(32, 32), dim3(256), 0, stream, qkvh, partial, pksum);
  hipLaunchKernelGGL(k_reduce,    dim3(32, 16), dim3(256), 0, stream, partial, pksum, attn_acc, ksum);
  hipLaunchKernelGGL(k_attn_proj, dim3(256),    dim3(256), 0, stream,
                     qkvh, attn_acc, ksum, temp, wprojh, bproj, attn1_out, y_out);
}

// Round 11
// 116.571 us; speedup vs baseline: 1.0533x; 1.0475x over previous
//
#include <hip/hip_runtime.h>
#include <cstdint>
#include <cstddef>

typedef _Float16 f16;
typedef _Float16 f16x4 __attribute__((ext_vector_type(4)));
typedef _Float16 f16x8 __attribute__((ext_vector_type(8)));
typedef float f32x4 __attribute__((ext_vector_type(4)));

#define MFMA16(a, b, c) __builtin_amdgcn_mfma_f32_16x16x32_f16(a, b, c, 0, 0, 0)

static __device__ __forceinline__ void gld16(const void* g, void* l) {
  __builtin_amdgcn_global_load_lds(
      (const __attribute__((address_space(1))) void*)g,
      (__attribute__((address_space(3))) void*)l, 16, 0, 0);
}

#define B_ 4
#define N_ 4096
#define C_ 512
#define H_ 8
#define D_ 64
#define BN_ROWS 16384
#define QKV_COLS 1536

// ---------------- kernel 1: fp32 -> fp16 convert (x, Wqkv, Wproj) ----------------
__global__ __launch_bounds__(256) void k_convert(
    const float* __restrict__ x, const float* __restrict__ wqkv,
    const float* __restrict__ wproj,
    f16* __restrict__ xh, f16* __restrict__ wqkvh, f16* __restrict__ wprojh)
{
  const int NX  = (BN_ROWS * C_) / 4;
  const int NW1 = (QKV_COLS * C_) / 4;
  const int NW2 = (C_ * C_) / 4;
  const int total = NX + NW1 + NW2;
  const int stride = gridDim.x * blockDim.x;
  for (int i = blockIdx.x * blockDim.x + threadIdx.x; i < total; i += stride) {
    const float4* s; f16x4* d; int j;
    if (i < NX)              { s = (const float4*)x;     d = (f16x4*)xh;     j = i; }
    else if (i < NX + NW1)   { s = (const float4*)wqkv;  d = (f16x4*)wqkvh;  j = i - NX; }
    else                     { s = (const float4*)wproj; d = (f16x4*)wprojh; j = i - NX - NW1; }
    float4 v = s[j];
    f16x4 o; o[0] = (f16)v.x; o[1] = (f16)v.y; o[2] = (f16)v.z; o[3] = (f16)v.w;
    d[j] = o;
  }
}

// ---------------- kernel 2: QKV GEMM — R2 exact (41.7us proven) ----------------
__global__ __launch_bounds__(256) void k_qkv_gemm(
    const f16* __restrict__ X, const f16* __restrict__ W, f16* __restrict__ Out)
{
  __shared__ f16 As[128][64];
  __shared__ f16 Bs[128][64];
  int w = (blockIdx.x & 7) * 192 + (blockIdx.x >> 3);
  const int n0 = (w % 12) * 128;
  const int m0 = (w / 12) * 128;
  const int tid = threadIdx.x;
  const int wid = tid >> 6;
  const int lane = tid & 63;
  const int lr = lane & 15, lg = lane >> 4;
  const int sr = lane >> 3;
  const int sslot = (lane & 7) ^ sr;
  const int wr = (wid >> 1) * 64, wc = (wid & 1) * 64;
  f32x4 acc[4][4] = {};
  for (int kt = 0; kt < 512; kt += 64) {
#pragma unroll
    for (int i = 0; i < 4; ++i) {
      int chunk = wid * 4 + i;
      int row = chunk * 8 + sr;
      gld16(&X[(size_t)(m0 + row) * 512 + kt + sslot * 8], &As[chunk * 8][0]);
      gld16(&W[(size_t)(n0 + row) * 512 + kt + sslot * 8], &Bs[chunk * 8][0]);
    }
    __syncthreads();
#pragma unroll
    for (int kk = 0; kk < 2; ++kk) {
      f16x8 af[4], bf[4];
#pragma unroll
      for (int m = 0; m < 4; ++m)
        af[m] = *(const f16x8*)&As[wr + m * 16 + lr][(((kk * 4 + lg) ^ (lr & 7)) * 8)];
#pragma unroll
      for (int n = 0; n < 4; ++n)
        bf[n] = *(const f16x8*)&Bs[wc + n * 16 + lr][(((kk * 4 + lg) ^ (lr & 7)) * 8)];
#pragma unroll
      for (int m = 0; m < 4; ++m)
#pragma unroll
        for (int n = 0; n < 4; ++n)
          acc[m][n] = MFMA16(bf[n], af[m], acc[m][n]);
    }
    __syncthreads();
  }
#pragma unroll
  for (int m = 0; m < 4; ++m)
#pragma unroll
    for (int n = 0; n < 4; ++n) {
      int row = m0 + wr + m * 16 + lr;
      int col = n0 + wc + n * 16 + lg * 4;
      f16x4 o;
      bool relu = (col < 1024);
#pragma unroll
      for (int j = 0; j < 4; ++j) {
        float v = acc[m][n][j];
        if (relu) v = fmaxf(v, 0.f);
        o[j] = (f16)v;
      }
      *(f16x4*)&Out[(size_t)row * QKV_COLS + col] = o;
    }
}

// ---------------- kernel 3: partial K^T V — 16 splits (2 blocks/CU, half traffic) ----------------
__global__ __launch_bounds__(256) void k_ktv(
    const f16* __restrict__ qkv, float* __restrict__ partial, float* __restrict__ pksum)
{
  __shared__ f16 ks[32][64];
  __shared__ f16 vs[32][64];
  const int bh = blockIdx.x, sp = blockIdx.y;
  const int b = bh >> 3, h = bh & 7;
  const int tid = threadIdx.x, wid = tid >> 6, lane = tid & 63;
  const int srow = lane >> 3, scol = (lane & 7) * 8;
  const int td = (wid << 2) | (lane >> 4);
  const int te = lane & 15;
  float acc[4][4] = {};
  float ksacc[4] = {0.f, 0.f, 0.f, 0.f};
  const size_t rowbase = (size_t)b * N_ + sp * 256;
  for (int t = 0; t < 8; ++t) {
    int nb = t * 32 + wid * 8 + srow;
    gld16(&qkv[(rowbase + nb) * QKV_COLS + 512 + h * 64 + scol], &ks[wid * 8][0]);
    gld16(&qkv[(rowbase + nb) * QKV_COLS + 1024 + h * 64 + scol], &vs[wid * 8][0]);
    __syncthreads();
#pragma unroll 4
    for (int n = 0; n < 32; ++n) {
      f16x4 kd = *(const f16x4*)&ks[n][td * 4];
      f16x4 ve = *(const f16x4*)&vs[n][te * 4];
      float kf[4], vf[4];
#pragma unroll
      for (int i = 0; i < 4; ++i) { kf[i] = (float)kd[i]; vf[i] = (float)ve[i]; }
#pragma unroll
      for (int i = 0; i < 4; ++i)
#pragma unroll
        for (int j = 0; j < 4; ++j)
          acc[i][j] += kf[i] * vf[j];
      if (te == 0) {
#pragma unroll
        for (int i = 0; i < 4; ++i) ksacc[i] += kf[i];
      }
    }
    __syncthreads();
  }
  float* pp = partial + (size_t)(bh * 16 + sp) * 4096;
#pragma unroll
  for (int i = 0; i < 4; ++i)
#pragma unroll
    for (int j = 0; j < 4; ++j)
      pp[(td * 4 + i) * 64 + te * 4 + j] = acc[i][j];
  if (te == 0) {
    float* kp = pksum + (bh * 16 + sp) * 64;
#pragma unroll
    for (int i = 0; i < 4; ++i) kp[td * 4 + i] = ksacc[i];
  }
}

// ---------------- kernel 4: reduce 16 partials (deterministic) ----------------
__global__ __launch_bounds__(256) void k_reduce(
    const float* __restrict__ partial, const float* __restrict__ pksum,
    float* __restrict__ attn_acc, float* __restrict__ ksum)
{
  const int bh = blockIdx.x, seg = blockIdx.y, tid = threadIdx.x;
  const int i = seg * 256 + tid;
  float s = 0.f;
#pragma unroll 8
  for (int sp = 0; sp < 16; ++sp) s += partial[(size_t)(bh * 16 + sp) * 4096 + i];
  attn_acc[bh * 4096 + i] = s;
  if (seg == 0 && tid < 64) {
    float t2 = 0.f;
#pragma unroll 8
    for (int sp = 0; sp < 16; ++sp) t2 += pksum[(bh * 16 + sp) * 64 + tid];
    ksum[bh * 64 + tid] = t2;
  }
}

// ---------------- kernel 5: FUSED attn1 + proj, wave-per-head Phase A ----------------
// 256 blocks (b x 64 row-splits of 64 rows), 256 thr (4 waves).
// Phase A: 2 batches x {wave wid handles head bi*4+wid alone: wave-private
//   attnT/qs slices, per-wave vmcnt wait, all-lane denom, 32 MFMA} — no
//   per-head barriers (2 total vs 16).
// Phase B: identical to R8 (Bs aliases the Phase-A slices via union).
__global__ __launch_bounds__(256, 1) void k_attn_proj(
    const f16* __restrict__ qkv, const float* __restrict__ attn_acc,
    const float* __restrict__ ksum, const float* __restrict__ temp,
    const f16* __restrict__ Wp, const float* __restrict__ bias,
    float* __restrict__ attn1_out, float* __restrict__ Y)
{
  __shared__ f16 outs[64][512];                         // 64KB (lives across phases)
  __shared__ union {
    struct { f16 attnT[4][64][64]; f16 qs[4][64][64]; } a;  // Phase A: 64KB
    f16 Bs[2][256][64];                                     // Phase B: 64KB
  } u;
  __shared__ float ksum_s[512];
  __shared__ float bias_s[512];
  __shared__ float denom_s[4][64];

  const int bid = blockIdx.x;
  const int b = bid >> 6, sp = bid & 63;
  const size_t gr = (size_t)b * N_ + sp * 64;
  const int tid = threadIdx.x;
  const int wid = tid >> 6, lane = tid & 63;
  const int lr = lane & 15, lg = lane >> 4;
  const int sr = lane >> 3, sslot = (lane & 7) ^ sr;

  ksum_s[tid]       = ksum[b * 512 + tid];
  ksum_s[tid + 256] = ksum[b * 512 + tid + 256];
  bias_s[tid]       = bias[tid];
  bias_s[tid + 256] = bias[tid + 256];
  __syncthreads();   // ksum_s ready for all waves

  // ================= Phase A: 2 batches, wave-per-head =================
#pragma unroll
  for (int bi = 0; bi < 2; ++bi) {
    const int h = bi * 4 + wid;
    const float tsc = temp[h];
    // stage q for this head (wave-private; dest wave-uniform base + lane*16)
#pragma unroll
    for (int rr = 0; rr < 8; ++rr)
      gld16(&qkv[(gr + rr * 8 + sr) * QKV_COLS + h * 64 + sslot * 8],
            &u.a.qs[wid][rr * 8][0]);
    // transpose-fill attnT[wid][e][swz(d)] = attn[d][e] * tsc  (lane = e)
#pragma unroll
    for (int dc = 0; dc < 4; ++dc) {
      float vals[16];
#pragma unroll
      for (int x = 0; x < 16; ++x)
        vals[x] = attn_acc[(size_t)(b * 8 + h) * 4096 + (dc * 16 + x) * 64 + lane] * tsc;
#pragma unroll
      for (int half = 0; half < 2; ++half) {
        int slot = (dc * 2 + half) ^ (lane & 7);
        f16x8 pk;
#pragma unroll
        for (int j = 0; j < 8; ++j) pk[j] = (f16)vals[half * 8 + j];
        *(f16x8*)&u.a.attnT[wid][lane][slot * 8] = pk;
      }
    }
    asm volatile("s_waitcnt vmcnt(0)" ::: "memory");   // q landed (per-wave counter)
    // denom: all 64 lanes, one row each
    {
      const int r = lane;
      float dot = 0.f;
#pragma unroll
      for (int c = 0; c < 8; ++c) {
        f16x8 qv = *(const f16x8*)&u.a.qs[wid][r][((c ^ (r & 7)) * 8)];
#pragma unroll
        for (int j = 0; j < 8; ++j) dot += (float)qv[j] * ksum_s[h * 64 + c * 8 + j];
      }
      denom_s[wid][r] = fmaxf(dot, 100.f);
    }
    // fragments + MFMA: wave computes full 64x64 for its head
    f16x8 af[2][4], bf[4][2];
#pragma unroll
    for (int kk = 0; kk < 2; ++kk)
#pragma unroll
      for (int m = 0; m < 4; ++m)
        af[kk][m] = *(const f16x8*)&u.a.qs[wid][m * 16 + lr][(((kk * 4 + lg) ^ (lr & 7)) * 8)];
#pragma unroll
    for (int et = 0; et < 4; ++et)
#pragma unroll
      for (int kk = 0; kk < 2; ++kk)
        bf[et][kk] = *(const f16x8*)&u.a.attnT[wid][et * 16 + lr][(((kk * 4 + lg) ^ (lr & 7)) * 8)];
    f32x4 acc1[4][4] = {};
#pragma unroll
    for (int kk = 0; kk < 2; ++kk)
#pragma unroll
      for (int m = 0; m < 4; ++m)
#pragma unroll
        for (int et = 0; et < 4; ++et)
          acc1[m][et] = MFMA16(bf[et][kk], af[kk][m], acc1[m][et]);  // swapped
    // epilogue: attn1_out + swizzled outs (wave-private columns h*64..h*64+63)
#pragma unroll
    for (int m = 0; m < 4; ++m) {
      const int rl = m * 16 + lr;
      const float dn = denom_s[wid][rl];
#pragma unroll
      for (int et = 0; et < 4; ++et) {
        int e = et * 16 + lg * 4;
        float4 o;
        o.x = acc1[m][et][0]; o.y = acc1[m][et][1]; o.z = acc1[m][et][2]; o.w = acc1[m][et][3];
        *(float4*)&attn1_out[((size_t)(b * 8 + h) * N_ + sp * 64 + rl) * 64 + e] = o;
        f16x4 oh;
#pragma unroll
        for (int j = 0; j < 4; ++j) oh[j] = (f16)(acc1[m][et][j] / dn);
        int c = h * 64 + e;
        *(f16x4*)((char*)&outs[0][0] + rl * 1024 +
                  (((c >> 3) ^ (rl & 7)) * 16) + (lg & 1) * 8) = oh;
      }
    }
  }
  __syncthreads();   // outs complete; u.a dead -> u.Bs live

  // ================= Phase B: proj (R8 exact) =================
  f32x4 accP0[4][4] = {};
  f32x4 accP1[4][4] = {};

#define STAGEP(hf_, kc_, bufi)                                                \
  do {                                                                        \
    _Pragma("unroll")                                                         \
    for (int rd = 0; rd < 8; ++rd) {                                          \
      int row = rd * 32 + wid * 8;                                            \
      gld16(&Wp[(size_t)((hf_) * 256 + row + sr) * 512 + (kc_) * 64 + sslot * 8], \
            &u.Bs[bufi][row][0]);                                             \
    }                                                                         \
  } while (0)

  STAGEP(0, 0, 0);
  __syncthreads();

  for (int kc = 0; kc < 8; ++kc) {
    STAGEP(1, kc, 1);
    f16x8 afp[2][4];
#pragma unroll
    for (int kk = 0; kk < 2; ++kk)
#pragma unroll
      for (int m = 0; m < 4; ++m) {
        int row = m * 16 + lr;
        afp[kk][m] = *(const f16x8*)((const char*)&outs[0][0] + row * 1024 +
                      (((kc * 8 + kk * 4 + lg) ^ (row & 7)) * 16));
      }
    {
      f16x8 bfp[4];
#pragma unroll
      for (int kk = 0; kk < 2; ++kk) {
#pragma unroll
        for (int n = 0; n < 4; ++n)
          bfp[n] = *(const f16x8*)&u.Bs[0][wid * 64 + n * 16 + lr][(((kk * 4 + lg) ^ (lr & 7)) * 8)];
#pragma unroll
        for (int m = 0; m < 4; ++m)
#pragma unroll
          for (int n = 0; n < 4; ++n)
            accP0[m][n] = MFMA16(bfp[n], afp[kk][m], accP0[m][n]);
      }
    }
    __syncthreads();
    if (kc < 7) STAGEP(0, kc + 1, 0);
    {
      f16x8 bfp[4];
#pragma unroll
      for (int kk = 0; kk < 2; ++kk) {
#pragma unroll
        for (int n = 0; n < 4; ++n)
          bfp[n] = *(const f16x8*)&u.Bs[1][wid * 64 + n * 16 + lr][(((kk * 4 + lg) ^ (lr & 7)) * 8)];
#pragma unroll
        for (int m = 0; m < 4; ++m)
#pragma unroll
          for (int n = 0; n < 4; ++n)
            accP1[m][n] = MFMA16(bfp[n], afp[kk][m], accP1[m][n]);
      }
    }
    __syncthreads();
  }
#undef STAGEP

#pragma unroll
  for (int m = 0; m < 4; ++m)
#pragma unroll
    for (int n = 0; n < 4; ++n) {
      size_t row = gr + m * 16 + lr;
      int col0 = wid * 64 + n * 16 + lg * 4;
      float4 o0;
      o0.x = accP0[m][n][0] + bias_s[col0 + 0];
      o0.y = accP0[m][n][1] + bias_s[col0 + 1];
      o0.z = accP0[m][n][2] + bias_s[col0 + 2];
      o0.w = accP0[m][n][3] + bias_s[col0 + 3];
      *(float4*)&Y[row * C_ + col0] = o0;
      int col1 = col0 + 256;
      float4 o1;
      o1.x = accP1[m][n][0] + bias_s[col1 + 0];
      o1.y = accP1[m][n][1] + bias_s[col1 + 1];
      o1.z = accP1[m][n][2] + bias_s[col1 + 2];
      o1.w = accP1[m][n][3] + bias_s[col1 + 3];
      *(float4*)&Y[row * C_ + col1] = o1;
    }
}

extern "C" void kernel_launch(void* const* d_in, const int* in_sizes, int n_in,
                              void* d_out, int out_size, void* d_ws, size_t ws_size,
                              hipStream_t stream)
{
  const float* x     = (const float*)d_in[0];
  const float* wqkv  = (const float*)d_in[1];
  const float* temp  = (const float*)d_in[2];
  const float* wproj = (const float*)d_in[3];
  const float* bproj = (const float*)d_in[4];
  float* y_out     = (float*)d_out;
  float* attn1_out = (float*)d_out + 8388608;

  char* ws = (char*)d_ws;
  f16*   xh       = (f16*)(ws);                   // 16 MB; reused as `partial` after QKV
  float* partial  = (float*)(ws);                 // aliases xh (xh dead once qkv done); 8 MB used
  f16*   wqkvh    = (f16*)(ws + 16777216);
  f16*   wprojh   = (f16*)(ws + 18350080);
  f16*   qkvh     = (f16*)(ws + 18874368);
  float* attn_acc = (float*)(ws + 69206016);
  float* ksum     = (float*)(ws + 69730304);
  float* pksum    = (float*)(ws + 69738496);

  hipLaunchKernelGGL(k_convert,   dim3(2048),   dim3(256), 0, stream, x, wqkv, wproj, xh, wqkvh, wprojh);
  hipLaunchKernelGGL(k_qkv_gemm,  dim3(1536),   dim3(256), 0, stream, xh, wqkvh, qkvh);
  hipLaunchKernelGGL(k_ktv,       dim3(32, 16), dim3(256), 0, stream, qkvh, partial, pksum);
  hipLaunchKernelGGL(k_reduce,    dim3(32, 16), dim3(256), 0, stream, partial, pksum, attn_acc, ksum);
  hipLaunchKernelGGL(k_attn_proj, dim3(256),    dim3(256), 0, stream,
                     qkvh, attn_acc, ksum, temp, wprojh, bproj, attn1_out, y_out);
}

// Round 12
// 111.411 us; speedup vs baseline: 1.1021x; 1.0463x over previous
//
#include <hip/hip_runtime.h>
#include <cstdint>
#include <cstddef>

typedef _Float16 f16;
typedef _Float16 f16x4 __attribute__((ext_vector_type(4)));
typedef _Float16 f16x8 __attribute__((ext_vector_type(8)));
typedef float f32x4 __attribute__((ext_vector_type(4)));
typedef __fp16 h2 __attribute__((ext_vector_type(2)));

#define MFMA16(a, b, c) __builtin_amdgcn_mfma_f32_16x16x32_f16(a, b, c, 0, 0, 0)

static __device__ __forceinline__ void gld16(const void* g, void* l) {
  __builtin_amdgcn_global_load_lds(
      (const __attribute__((address_space(1))) void*)g,
      (__attribute__((address_space(3))) void*)l, 16, 0, 0);
}

static __device__ __forceinline__ h2 as_h2(uint32_t u) {
  union { uint32_t u; h2 h; } c; c.u = u; return c.h;
}

#define B_ 4
#define N_ 4096
#define C_ 512
#define H_ 8
#define D_ 64
#define BN_ROWS 16384
#define QKV_COLS 1536

// ---------------- kernel 1: fp32 -> fp16 convert (x, Wqkv, Wproj) ----------------
__global__ __launch_bounds__(256) void k_convert(
    const float* __restrict__ x, const float* __restrict__ wqkv,
    const float* __restrict__ wproj,
    f16* __restrict__ xh, f16* __restrict__ wqkvh, f16* __restrict__ wprojh)
{
  const int NX  = (BN_ROWS * C_) / 4;
  const int NW1 = (QKV_COLS * C_) / 4;
  const int NW2 = (C_ * C_) / 4;
  const int total = NX + NW1 + NW2;
  const int stride = gridDim.x * blockDim.x;
  for (int i = blockIdx.x * blockDim.x + threadIdx.x; i < total; i += stride) {
    const float4* s; f16x4* d; int j;
    if (i < NX)              { s = (const float4*)x;     d = (f16x4*)xh;     j = i; }
    else if (i < NX + NW1)   { s = (const float4*)wqkv;  d = (f16x4*)wqkvh;  j = i - NX; }
    else                     { s = (const float4*)wproj; d = (f16x4*)wprojh; j = i - NX - NW1; }
    float4 v = s[j];
    f16x4 o; o[0] = (f16)v.x; o[1] = (f16)v.y; o[2] = (f16)v.z; o[3] = (f16)v.w;
    d[j] = o;
  }
}

// ---------------- kernel 2: QKV GEMM — R2 exact (41.7us proven) ----------------
__global__ __launch_bounds__(256) void k_qkv_gemm(
    const f16* __restrict__ X, const f16* __restrict__ W, f16* __restrict__ Out)
{
  __shared__ f16 As[128][64];
  __shared__ f16 Bs[128][64];
  int w = (blockIdx.x & 7) * 192 + (blockIdx.x >> 3);
  const int n0 = (w % 12) * 128;
  const int m0 = (w / 12) * 128;
  const int tid = threadIdx.x;
  const int wid = tid >> 6;
  const int lane = tid & 63;
  const int lr = lane & 15, lg = lane >> 4;
  const int sr = lane >> 3;
  const int sslot = (lane & 7) ^ sr;
  const int wr = (wid >> 1) * 64, wc = (wid & 1) * 64;
  f32x4 acc[4][4] = {};
  for (int kt = 0; kt < 512; kt += 64) {
#pragma unroll
    for (int i = 0; i < 4; ++i) {
      int chunk = wid * 4 + i;
      int row = chunk * 8 + sr;
      gld16(&X[(size_t)(m0 + row) * 512 + kt + sslot * 8], &As[chunk * 8][0]);
      gld16(&W[(size_t)(n0 + row) * 512 + kt + sslot * 8], &Bs[chunk * 8][0]);
    }
    __syncthreads();
#pragma unroll
    for (int kk = 0; kk < 2; ++kk) {
      f16x8 af[4], bf[4];
#pragma unroll
      for (int m = 0; m < 4; ++m)
        af[m] = *(const f16x8*)&As[wr + m * 16 + lr][(((kk * 4 + lg) ^ (lr & 7)) * 8)];
#pragma unroll
      for (int n = 0; n < 4; ++n)
        bf[n] = *(const f16x8*)&Bs[wc + n * 16 + lr][(((kk * 4 + lg) ^ (lr & 7)) * 8)];
#pragma unroll
      for (int m = 0; m < 4; ++m)
#pragma unroll
        for (int n = 0; n < 4; ++n)
          acc[m][n] = MFMA16(bf[n], af[m], acc[m][n]);
    }
    __syncthreads();
  }
#pragma unroll
  for (int m = 0; m < 4; ++m)
#pragma unroll
    for (int n = 0; n < 4; ++n) {
      int row = m0 + wr + m * 16 + lr;
      int col = n0 + wc + n * 16 + lg * 4;
      f16x4 o;
      bool relu = (col < 1024);
#pragma unroll
      for (int j = 0; j < 4; ++j) {
        float v = acc[m][n][j];
        if (relu) v = fmaxf(v, 0.f);
        o[j] = (f16)v;
      }
      *(f16x4*)&Out[(size_t)row * QKV_COLS + col] = o;
    }
}

// ---------------- kernel 3: partial K^T V — fdot2 (4 FLOP/instr) ----------------
// 16 splits (2 blocks/CU). Pairs of n rows packed via v_perm -> v_dot2_f32_f16.
// Per 2n: 4 b64 reads + 8 perm + 16 fdot2 (vs 16 cvt + 32 fma before).
__global__ __launch_bounds__(256) void k_ktv(
    const f16* __restrict__ qkv, float* __restrict__ partial, float* __restrict__ pksum)
{
  __shared__ f16 ks[32][64];
  __shared__ f16 vs[32][64];
  const int bh = blockIdx.x, sp = blockIdx.y;
  const int b = bh >> 3, h = bh & 7;
  const int tid = threadIdx.x, wid = tid >> 6, lane = tid & 63;
  const int srow = lane >> 3, scol = (lane & 7) * 8;
  const int td = (wid << 2) | (lane >> 4);
  const int te = lane & 15;
  const uint32_t SEL_LO = 0x05040100u, SEL_HI = 0x07060302u;
  const h2 ones = {(__fp16)1.0f, (__fp16)1.0f};
  float acc[4][4] = {};
  float ksacc[4] = {0.f, 0.f, 0.f, 0.f};
  const size_t rowbase = (size_t)b * N_ + sp * 256;
  for (int t = 0; t < 8; ++t) {
    int nb = t * 32 + wid * 8 + srow;
    gld16(&qkv[(rowbase + nb) * QKV_COLS + 512 + h * 64 + scol], &ks[wid * 8][0]);
    gld16(&qkv[(rowbase + nb) * QKV_COLS + 1024 + h * 64 + scol], &vs[wid * 8][0]);
    __syncthreads();
#pragma unroll 4
    for (int n = 0; n < 32; n += 2) {
      uint2 ka = *(const uint2*)&ks[n][td * 4];
      uint2 kb = *(const uint2*)&ks[n + 1][td * 4];
      uint2 va = *(const uint2*)&vs[n][te * 4];
      uint2 vb = *(const uint2*)&vs[n + 1][te * 4];
      uint32_t kp[4], vp[4];
      kp[0] = __builtin_amdgcn_perm(kb.x, ka.x, SEL_LO);
      kp[1] = __builtin_amdgcn_perm(kb.x, ka.x, SEL_HI);
      kp[2] = __builtin_amdgcn_perm(kb.y, ka.y, SEL_LO);
      kp[3] = __builtin_amdgcn_perm(kb.y, ka.y, SEL_HI);
      vp[0] = __builtin_amdgcn_perm(vb.x, va.x, SEL_LO);
      vp[1] = __builtin_amdgcn_perm(vb.x, va.x, SEL_HI);
      vp[2] = __builtin_amdgcn_perm(vb.y, va.y, SEL_LO);
      vp[3] = __builtin_amdgcn_perm(vb.y, va.y, SEL_HI);
#pragma unroll
      for (int i = 0; i < 4; ++i)
#pragma unroll
        for (int j = 0; j < 4; ++j)
          acc[i][j] = __builtin_amdgcn_fdot2(as_h2(kp[i]), as_h2(vp[j]), acc[i][j], false);
      if (te == 0) {
#pragma unroll
        for (int i = 0; i < 4; ++i)
          ksacc[i] = __builtin_amdgcn_fdot2(as_h2(kp[i]), ones, ksacc[i], false);
      }
    }
    __syncthreads();
  }
  float* pp = partial + (size_t)(bh * 16 + sp) * 4096;
#pragma unroll
  for (int i = 0; i < 4; ++i)
#pragma unroll
    for (int j = 0; j < 4; ++j)
      pp[(td * 4 + i) * 64 + te * 4 + j] = acc[i][j];
  if (te == 0) {
    float* kp2 = pksum + (bh * 16 + sp) * 64;
#pragma unroll
    for (int i = 0; i < 4; ++i) kp2[td * 4 + i] = ksacc[i];
  }
}

// ---------------- kernel 4: reduce 16 partials (deterministic) ----------------
__global__ __launch_bounds__(256) void k_reduce(
    const float* __restrict__ partial, const float* __restrict__ pksum,
    float* __restrict__ attn_acc, float* __restrict__ ksum)
{
  const int bh = blockIdx.x, seg = blockIdx.y, tid = threadIdx.x;
  const int i = seg * 256 + tid;
  float s = 0.f;
#pragma unroll 8
  for (int sp = 0; sp < 16; ++sp) s += partial[(size_t)(bh * 16 + sp) * 4096 + i];
  attn_acc[bh * 4096 + i] = s;
  if (seg == 0 && tid < 64) {
    float t2 = 0.f;
#pragma unroll 8
    for (int sp = 0; sp < 16; ++sp) t2 += pksum[(bh * 16 + sp) * 64 + tid];
    ksum[bh * 64 + tid] = t2;
  }
}

// ---------------- kernel 5: FUSED attn1 + proj, wave-per-head Phase A — R11 exact ----------------
__global__ __launch_bounds__(256, 1) void k_attn_proj(
    const f16* __restrict__ qkv, const float* __restrict__ attn_acc,
    const float* __restrict__ ksum, const float* __restrict__ temp,
    const f16* __restrict__ Wp, const float* __restrict__ bias,
    float* __restrict__ attn1_out, float* __restrict__ Y)
{
  __shared__ f16 outs[64][512];
  __shared__ union {
    struct { f16 attnT[4][64][64]; f16 qs[4][64][64]; } a;
    f16 Bs[2][256][64];
  } u;
  __shared__ float ksum_s[512];
  __shared__ float bias_s[512];
  __shared__ float denom_s[4][64];

  const int bid = blockIdx.x;
  const int b = bid >> 6, sp = bid & 63;
  const size_t gr = (size_t)b * N_ + sp * 64;
  const int tid = threadIdx.x;
  const int wid = tid >> 6, lane = tid & 63;
  const int lr = lane & 15, lg = lane >> 4;
  const int sr = lane >> 3, sslot = (lane & 7) ^ sr;

  ksum_s[tid]       = ksum[b * 512 + tid];
  ksum_s[tid + 256] = ksum[b * 512 + tid + 256];
  bias_s[tid]       = bias[tid];
  bias_s[tid + 256] = bias[tid + 256];
  __syncthreads();

  // ================= Phase A: 2 batches, wave-per-head =================
#pragma unroll
  for (int bi = 0; bi < 2; ++bi) {
    const int h = bi * 4 + wid;
    const float tsc = temp[h];
#pragma unroll
    for (int rr = 0; rr < 8; ++rr)
      gld16(&qkv[(gr + rr * 8 + sr) * QKV_COLS + h * 64 + sslot * 8],
            &u.a.qs[wid][rr * 8][0]);
#pragma unroll
    for (int dc = 0; dc < 4; ++dc) {
      float vals[16];
#pragma unroll
      for (int x = 0; x < 16; ++x)
        vals[x] = attn_acc[(size_t)(b * 8 + h) * 4096 + (dc * 16 + x) * 64 + lane] * tsc;
#pragma unroll
      for (int half = 0; half < 2; ++half) {
        int slot = (dc * 2 + half) ^ (lane & 7);
        f16x8 pk;
#pragma unroll
        for (int j = 0; j < 8; ++j) pk[j] = (f16)vals[half * 8 + j];
        *(f16x8*)&u.a.attnT[wid][lane][slot * 8] = pk;
      }
    }
    asm volatile("s_waitcnt vmcnt(0)" ::: "memory");
    {
      const int r = lane;
      float dot = 0.f;
#pragma unroll
      for (int c = 0; c < 8; ++c) {
        f16x8 qv = *(const f16x8*)&u.a.qs[wid][r][((c ^ (r & 7)) * 8)];
#pragma unroll
        for (int j = 0; j < 8; ++j) dot += (float)qv[j] * ksum_s[h * 64 + c * 8 + j];
      }
      denom_s[wid][r] = fmaxf(dot, 100.f);
    }
    f16x8 af[2][4], bf[4][2];
#pragma unroll
    for (int kk = 0; kk < 2; ++kk)
#pragma unroll
      for (int m = 0; m < 4; ++m)
        af[kk][m] = *(const f16x8*)&u.a.qs[wid][m * 16 + lr][(((kk * 4 + lg) ^ (lr & 7)) * 8)];
#pragma unroll
    for (int et = 0; et < 4; ++et)
#pragma unroll
      for (int kk = 0; kk < 2; ++kk)
        bf[et][kk] = *(const f16x8*)&u.a.attnT[wid][et * 16 + lr][(((kk * 4 + lg) ^ (lr & 7)) * 8)];
    f32x4 acc1[4][4] = {};
#pragma unroll
    for (int kk = 0; kk < 2; ++kk)
#pragma unroll
      for (int m = 0; m < 4; ++m)
#pragma unroll
        for (int et = 0; et < 4; ++et)
          acc1[m][et] = MFMA16(bf[et][kk], af[kk][m], acc1[m][et]);
#pragma unroll
    for (int m = 0; m < 4; ++m) {
      const int rl = m * 16 + lr;
      const float dn = denom_s[wid][rl];
#pragma unroll
      for (int et = 0; et < 4; ++et) {
        int e = et * 16 + lg * 4;
        float4 o;
        o.x = acc1[m][et][0]; o.y = acc1[m][et][1]; o.z = acc1[m][et][2]; o.w = acc1[m][et][3];
        *(float4*)&attn1_out[((size_t)(b * 8 + h) * N_ + sp * 64 + rl) * 64 + e] = o;
        f16x4 oh;
#pragma unroll
        for (int j = 0; j < 4; ++j) oh[j] = (f16)(acc1[m][et][j] / dn);
        int c = h * 64 + e;
        *(f16x4*)((char*)&outs[0][0] + rl * 1024 +
                  (((c >> 3) ^ (rl & 7)) * 16) + (lg & 1) * 8) = oh;
      }
    }
  }
  __syncthreads();

  // ================= Phase B: proj =================
  f32x4 accP0[4][4] = {};
  f32x4 accP1[4][4] = {};

#define STAGEP(hf_, kc_, bufi)                                                \
  do {                                                                        \
    _Pragma("unroll")                                                         \
    for (int rd = 0; rd < 8; ++rd) {                                          \
      int row = rd * 32 + wid * 8;                                            \
      gld16(&Wp[(size_t)((hf_) * 256 + row + sr) * 512 + (kc_) * 64 + sslot * 8], \
            &u.Bs[bufi][row][0]);                                             \
    }                                                                         \
  } while (0)

  STAGEP(0, 0, 0);
  __syncthreads();

  for (int kc = 0; kc < 8; ++kc) {
    STAGEP(1, kc, 1);
    f16x8 afp[2][4];
#pragma unroll
    for (int kk = 0; kk < 2; ++kk)
#pragma unroll
      for (int m = 0; m < 4; ++m) {
        int row = m * 16 + lr;
        afp[kk][m] = *(const f16x8*)((const char*)&outs[0][0] + row * 1024 +
                      (((kc * 8 + kk * 4 + lg) ^ (row & 7)) * 16));
      }
    {
      f16x8 bfp[4];
#pragma unroll
      for (int kk = 0; kk < 2; ++kk) {
#pragma unroll
        for (int n = 0; n < 4; ++n)
          bfp[n] = *(const f16x8*)&u.Bs[0][wid * 64 + n * 16 + lr][(((kk * 4 + lg) ^ (lr & 7)) * 8)];
#pragma unroll
        for (int m = 0; m < 4; ++m)
#pragma unroll
          for (int n = 0; n < 4; ++n)
            accP0[m][n] = MFMA16(bfp[n], afp[kk][m], accP0[m][n]);
      }
    }
    __syncthreads();
    if (kc < 7) STAGEP(0, kc + 1, 0);
    {
      f16x8 bfp[4];
#pragma unroll
      for (int kk = 0; kk < 2; ++kk) {
#pragma unroll
        for (int n = 0; n < 4; ++n)
          bfp[n] = *(const f16x8*)&u.Bs[1][wid * 64 + n * 16 + lr][(((kk * 4 + lg) ^ (lr & 7)) * 8)];
#pragma unroll
        for (int m = 0; m < 4; ++m)
#pragma unroll
          for (int n = 0; n < 4; ++n)
            accP1[m][n] = MFMA16(bfp[n], afp[kk][m], accP1[m][n]);
      }
    }
    __syncthreads();
  }
#undef STAGEP

#pragma unroll
  for (int m = 0; m < 4; ++m)
#pragma unroll
    for (int n = 0; n < 4; ++n) {
      size_t row = gr + m * 16 + lr;
      int col0 = wid * 64 + n * 16 + lg * 4;
      float4 o0;
      o0.x = accP0[m][n][0] + bias_s[col0 + 0];
      o0.y = accP0[m][n][1] + bias_s[col0 + 1];
      o0.z = accP0[m][n][2] + bias_s[col0 + 2];
      o0.w = accP0[m][n][3] + bias_s[col0 + 3];
      *(float4*)&Y[row * C_ + col0] = o0;
      int col1 = col0 + 256;
      float4 o1;
      o1.x = accP1[m][n][0] + bias_s[col1 + 0];
      o1.y = accP1[m][n][1] + bias_s[col1 + 1];
      o1.z = accP1[m][n][2] + bias_s[col1 + 2];
      o1.w = accP1[m][n][3] + bias_s[col1 + 3];
      *(float4*)&Y[row * C_ + col1] = o1;
    }
}

extern "C" void kernel_launch(void* const* d_in, const int* in_sizes, int n_in,
                              void* d_out, int out_size, void* d_ws, size_t ws_size,
                              hipStream_t stream)
{
  const float* x     = (const float*)d_in[0];
  const float* wqkv  = (const float*)d_in[1];
  const float* temp  = (const float*)d_in[2];
  const float* wproj = (const float*)d_in[3];
  const float* bproj = (const float*)d_in[4];
  float* y_out     = (float*)d_out;
  float* attn1_out = (float*)d_out + 8388608;

  char* ws = (char*)d_ws;
  f16*   xh       = (f16*)(ws);                   // 16 MB; reused as `partial` after QKV
  float* partial  = (float*)(ws);                 // aliases xh (xh dead once qkv done); 8 MB used
  f16*   wqkvh    = (f16*)(ws + 16777216);
  f16*   wprojh   = (f16*)(ws + 18350080);
  f16*   qkvh     = (f16*)(ws + 18874368);
  float* attn_acc = (float*)(ws + 69206016);
  float* ksum     = (float*)(ws + 69730304);
  float* pksum    = (float*)(ws + 69738496);

  hipLaunchKernelGGL(k_convert,   dim3(2048),   dim3(256), 0, stream, x, wqkv, wproj, xh, wqkvh, wprojh);
  hipLaunchKernelGGL(k_qkv_gemm,  dim3(1536),   dim3(256), 0, stream, xh, wqkvh, qkvh);
  hipLaunchKernelGGL(k_ktv,       dim3(32, 16), dim3(256), 0, stream, qkvh, partial, pksum);
  hipLaunchKernelGGL(k_reduce,    dim3(32, 16), dim3(256), 0, stream, partial, pksum, attn_acc, ksum);
  hipLaunchKernelGGL(k_attn_proj, dim3(256),    dim3(256), 0, stream,
                     qkvh, attn_acc, ksum, temp, wprojh, bproj, attn1_out, y_out);
}